// Round 2
// baseline (24475.108 us; speedup 1.0000x reference)
//
#include <hip/hip_runtime.h>
#include <hip/hip_bf16.h>

// 5-layer LSTM, B=64, T=256, H=1024. bf16 MFMA (16x16x32), fp32 state.
// Round 2: ONE persistent cooperative kernel for the whole recurrence.
//  - weights held in VGPRs (128/wave), loaded once per layer
//  - split arrive/wait grid barrier per timestep, hidden behind next-step
//    x-part GEMM (which doesn't depend on h)
//  - two independent barrier groups (batch halves are fully independent)
//  - cell state in registers (one float per epilogue thread)

using bf16x8 = __attribute__((ext_vector_type(8))) __bf16;
using f32x4  = __attribute__((ext_vector_type(4))) float;

#define Tn 256
#define Bn 64
#define Hn 1024

#define MFMA16(a, b, c) __builtin_amdgcn_mfma_f32_16x16x32_bf16((a), (b), (c), 0, 0, 0)

// ---------------------------------------------------------------------------
// Wg[l][k][unit] (fp32, [5][2048][1024] per gate) -> Wperm[l][cb][col][k] bf16
// cb = 0..127 (8 units each), col = g*8 + uu (g = gate, uu = unit within cb),
// k = 0..2047 (0..1023 x-part, 1024..2047 h-part). k innermost for B-frags.
__global__ void convW(const float* __restrict__ Wi, const float* __restrict__ Wf,
                      const float* __restrict__ Wc, const float* __restrict__ Wo,
                      __bf16* __restrict__ Wperm) {
    int gid = blockIdx.x * 256 + threadIdx.x;      // 5*128*32*256 = 5,242,880
    int k8  = gid & 255;                           // 256 chunks of 8 k
    int col = (gid >> 8) & 31;
    int cb  = (gid >> 13) & 127;
    int l   = gid >> 20;
    int g   = col >> 3;
    int uu  = col & 7;
    int unit = cb * 8 + uu;
    const float* Wg = (g == 0) ? Wi : (g == 1) ? Wf : (g == 2) ? Wc : Wo;
    const float* src = Wg + ((size_t)l * 2048 + k8 * 8) * 1024 + unit;
    bf16x8 v;
#pragma unroll
    for (int j = 0; j < 8; ++j) v[j] = (__bf16)src[(size_t)j * 1024];
    *(bf16x8*)(Wperm + (size_t)gid * 8) = v;
}

// x[b][t][k] fp32 -> seq[t][b][k] bf16
__global__ void convX(const float* __restrict__ x, __bf16* __restrict__ seq) {
    int gid = blockIdx.x * 256 + threadIdx.x;      // 256*64*128 = 2,097,152
    int k8 = gid & 127;
    int b  = (gid >> 7) & 63;
    int t  = gid >> 13;
    const float* src = x + ((size_t)b * Tn + t) * Hn + k8 * 8;
    bf16x8 v;
#pragma unroll
    for (int j = 0; j < 8; ++j) v[j] = (__bf16)src[j];
    *(bf16x8*)(seq + (size_t)gid * 8) = v;
}

__global__ void init_bar(unsigned* bar) { bar[threadIdx.x] = 0u; }

// ---------------------------------------------------------------------------
// Persistent kernel. 256 blocks x 512 threads, 1 block/CU.
// bid: rb = bid&1 (batch half, 32 rows), cb = bid>>1 (32 gate-cols = 8 units).
// waves: kg = w&3 (512-wide K slice: 256 of x + 256 of h), mg = w>>2 (16 rows).
__global__ __launch_bounds__(512, 2) void lstm_all(
    __bf16* __restrict__ seqA, __bf16* __restrict__ seqB,
    const __bf16* __restrict__ Wperm,
    const float* __restrict__ bip, const float* __restrict__ bfp,
    const float* __restrict__ bcp, const float* __restrict__ bop,
    unsigned* __restrict__ bar) {
    __shared__ float zp[4 * 32 * 36];              // [kg][row32][36] padded

    const int tid  = threadIdx.x;
    const int bid  = blockIdx.x;
    const int rb   = bid & 1;
    const int cb   = bid >> 1;
    const int w    = tid >> 6;
    const int lane = tid & 63;
    const int kg   = w & 3;
    const int mg   = w >> 2;
    const int l15  = lane & 15;
    const int lhi  = lane >> 4;
    const int arow = rb * 32 + mg * 16 + l15;      // batch row for A-frags
    const int ep_uu = tid & 7, ep_b = tid >> 3;    // epilogue map (tid<256)

    unsigned* cnt = bar + rb * 128;                // per-half barrier group
    unsigned* gen = bar + rb * 128 + 64;

    __bf16* inp  = seqA;
    __bf16* outp = seqB;
    const f32x4 vzero = {};

    for (int l = 0; l < 5; ++l) {
        // ---- load this layer's B-fragments (weights) into registers
        const __bf16* Wl = Wperm + (((size_t)l * 128 + cb) << 16);
        bf16x8 bx[2][8], bh[2][8];
#pragma unroll
        for (int nf = 0; nf < 2; ++nf) {
            const __bf16* wcol = Wl + (size_t)(16 * nf + l15) * 2048 + kg * 256 + lhi * 8;
#pragma unroll
            for (int kt = 0; kt < 8; ++kt) {
                bx[nf][kt] = *(const bf16x8*)(wcol + kt * 32);
                bh[nf][kt] = *(const bf16x8*)(wcol + 1024 + kt * 32);
            }
        }
        // ---- per-layer epilogue constants + cell state (registers)
        float bia0 = 0.f, bia1 = 0.f, bia2 = 0.f, bia3 = 0.f, creg = 0.f;
        if (tid < 256) {
            int unit = cb * 8 + ep_uu;
            bia0 = bip[l * 1024 + unit];
            bia1 = bfp[l * 1024 + unit];
            bia2 = bcp[l * 1024 + unit];
            bia3 = bop[l * 1024 + unit];
        }

        f32x4 acc[2];
        acc[0] = vzero; acc[1] = vzero;
        {   // x-part for t = 0
            const __bf16* ax = inp + (size_t)arow * Hn + kg * 256 + lhi * 8;
#pragma unroll
            for (int kt = 0; kt < 8; ++kt) {
                bf16x8 a = *(const bf16x8*)(ax + kt * 32);
                acc[0] = MFMA16(a, bx[0][kt], acc[0]);
                acc[1] = MFMA16(a, bx[1][kt], acc[1]);
            }
        }

        for (int t = 0; t < Tn; ++t) {
            if (t > 0) {
                // ---- wait: h[t-1] of our batch half fully published
                if (tid == 0) {
                    unsigned target = (unsigned)(l * Tn + t);
                    while (__hip_atomic_load(gen, __ATOMIC_RELAXED,
                                             __HIP_MEMORY_SCOPE_AGENT) < target)
                        __builtin_amdgcn_s_sleep(4);
                    __threadfence();               // acquire: inv L1 + L2
                }
                __syncthreads();
                // ---- h-part GEMM for step t
                const __bf16* ah = outp + ((size_t)(t - 1) * Bn + arow) * Hn
                                        + kg * 256 + lhi * 8;
#pragma unroll
                for (int kt = 0; kt < 8; ++kt) {
                    bf16x8 a = *(const bf16x8*)(ah + kt * 32);
                    acc[0] = MFMA16(a, bh[0][kt], acc[0]);
                    acc[1] = MFMA16(a, bh[1][kt], acc[1]);
                }
            }
            // ---- publish partials (D row = 4*lhi+j, col = 16*nf+l15)
#pragma unroll
            for (int nf = 0; nf < 2; ++nf)
#pragma unroll
                for (int j = 0; j < 4; ++j)
                    zp[(kg * 32 + mg * 16 + 4 * lhi + j) * 36 + 16 * nf + l15] =
                        acc[nf][j];
            __syncthreads();
            // ---- reduce + gates + state update (waves 0-3)
            if (tid < 256) {
                float z0 = bia0, z1 = bia1, z2 = bia2, z3 = bia3;
#pragma unroll
                for (int k2 = 0; k2 < 4; ++k2) {
                    const float* zr = zp + k2 * 1152 + ep_b * 36 + ep_uu;
                    z0 += zr[0]; z1 += zr[8]; z2 += zr[16]; z3 += zr[24];
                }
                float ii = 1.f / (1.f + expf(-z0));
                float ff = 1.f / (1.f + expf(-z1));
                float gg = tanhf(z2);
                float oo = 1.f / (1.f + expf(-z3));
                creg = creg * ff + ii * gg;
                float hv = oo * tanhf(creg);
                outp[((size_t)t * Bn + rb * 32 + ep_b) * Hn + cb * 8 + ep_uu] =
                    (__bf16)hv;
            }
            __syncthreads();                       // h stores drained (vmcnt)
            // ---- arrive (release h[t] to the other blocks of this half)
            if (tid == 0) {
                __threadfence();                   // wb L2 to coherence point
                unsigned old = __hip_atomic_fetch_add(cnt, 1u, __ATOMIC_ACQ_REL,
                                                      __HIP_MEMORY_SCOPE_AGENT);
                if (old == 127u) {
                    __hip_atomic_store(cnt, 0u, __ATOMIC_RELAXED,
                                       __HIP_MEMORY_SCOPE_AGENT);
                    __hip_atomic_fetch_add(gen, 1u, __ATOMIC_RELEASE,
                                           __HIP_MEMORY_SCOPE_AGENT);
                }
            }
            // ---- x-part GEMM for t+1 (independent of h -> hides barrier)
            acc[0] = vzero; acc[1] = vzero;
            if (t < Tn - 1) {
                const __bf16* ax = inp + ((size_t)(t + 1) * Bn + arow) * Hn
                                       + kg * 256 + lhi * 8;
#pragma unroll
                for (int kt = 0; kt < 8; ++kt) {
                    bf16x8 a = *(const bf16x8*)(ax + kt * 32);
                    acc[0] = MFMA16(a, bx[0][kt], acc[0]);
                    acc[1] = MFMA16(a, bx[1][kt], acc[1]);
                }
            }
        }
        __bf16* tmp = outp; outp = inp; inp = tmp; // ping-pong
    }
}

// ---------------------------------------------------------------------------
// out[b] = dot(h5[T-1][b][:], Wfc) + bfc
__global__ void fc_kernel(const __bf16* __restrict__ seq, const float* __restrict__ Wfc,
                          const float* __restrict__ bfc, float* __restrict__ out) {
    int b = blockIdx.x;
    int tid = threadIdx.x;
    const __bf16* h = seq + ((size_t)(Tn - 1) * Bn + b) * Hn;
    float s = 0.f;
    for (int k = tid; k < Hn; k += 256) s += (float)h[k] * Wfc[k];
#pragma unroll
    for (int off = 32; off > 0; off >>= 1) s += __shfl_down(s, off);
    __shared__ float red[4];
    if ((tid & 63) == 0) red[tid >> 6] = s;
    __syncthreads();
    if (tid == 0) out[b] = red[0] + red[1] + red[2] + red[3] + bfc[0];
}

// ---------------------------------------------------------------------------
extern "C" void kernel_launch(void* const* d_in, const int* in_sizes, int n_in,
                              void* d_out, int out_size, void* d_ws, size_t ws_size,
                              hipStream_t stream) {
    const float* x   = (const float*)d_in[0];
    const float* Wi  = (const float*)d_in[1];
    const float* bi  = (const float*)d_in[2];
    const float* Wf  = (const float*)d_in[3];
    const float* bf  = (const float*)d_in[4];
    const float* Wc  = (const float*)d_in[5];
    const float* bc  = (const float*)d_in[6];
    const float* Wo  = (const float*)d_in[7];
    const float* bo  = (const float*)d_in[8];
    const float* Wfc = (const float*)d_in[9];
    const float* bfc = (const float*)d_in[10];

    char* ws = (char*)d_ws;
    __bf16*   Wperm = (__bf16*)ws;                                 // 83,886,080 B
    __bf16*   seqA  = (__bf16*)(ws + 83886080);                    // 33,554,432 B
    __bf16*   seqB  = (__bf16*)(ws + 83886080 + 33554432);         // 33,554,432 B
    unsigned* bar   = (unsigned*)(ws + 83886080 + 2 * 33554432);   //      1,024 B

    hipLaunchKernelGGL(convW, dim3(20480), dim3(256), 0, stream, Wi, Wf, Wc, Wo, Wperm);
    hipLaunchKernelGGL(convX, dim3(8192), dim3(256), 0, stream, x, seqA);
    hipLaunchKernelGGL(init_bar, dim3(1), dim3(256), 0, stream, bar);

    void* args[] = {(void*)&seqA, (void*)&seqB, (void*)&Wperm,
                    (void*)&bi, (void*)&bf, (void*)&bc, (void*)&bo, (void*)&bar};
    hipLaunchCooperativeKernel((const void*)lstm_all, dim3(256), dim3(512),
                               args, 0, stream);

    // after 5 ping-pongs the final hidden sequence is in seqB
    hipLaunchKernelGGL(fc_kernel, dim3(64), dim3(256), 0, stream, seqB, Wfc, bfc,
                       (float*)d_out);
}

// Round 3
// 24084.688 us; speedup vs baseline: 1.0162x; 1.0162x over previous
//
#include <hip/hip_runtime.h>
#include <hip/hip_bf16.h>

// 5-layer LSTM, B=64, T=256, H=1024. bf16 MFMA (16x16x32), fp32 state.
// Round 3: persistent cooperative kernel, weights resident in LDS (swizzled),
// flag-array split barrier (no atomic chains), per-half decoupling.

using bf16x8 = __attribute__((ext_vector_type(8))) __bf16;
using f32x4  = __attribute__((ext_vector_type(4))) float;

#define Tn 256
#define Bn 64
#define Hn 1024

#define MFMA16(a, b, c) __builtin_amdgcn_mfma_f32_16x16x32_bf16((a), (b), (c), 0, 0, 0)

// ---------------------------------------------------------------------------
// Wg[l][k][unit] (fp32) -> Wperm: per (l, cb) a 128 KiB slab, element (col,k)
// at byte (col*4096 + k*2) ^ ((col&7)<<4).  col = g*8+uu (32 cols of 2048 k).
// The XOR pre-swizzle makes the later LDS image bank-conflict-free for
// ds_read_b128 B-fragments (lanes read different cols at same k-window).
__global__ void convW(const float* __restrict__ Wi, const float* __restrict__ Wf,
                      const float* __restrict__ Wc, const float* __restrict__ Wo,
                      __bf16* __restrict__ Wperm) {
    int gid = blockIdx.x * 256 + threadIdx.x;      // 5*128*32*256 = 5,242,880
    int k8  = gid & 255;                           // 8-k chunk
    int col = (gid >> 8) & 31;
    int cb  = (gid >> 13) & 127;
    int l   = gid >> 20;
    int g   = col >> 3;
    int uu  = col & 7;
    int unit = cb * 8 + uu;
    const float* Wg = (g == 0) ? Wi : (g == 1) ? Wf : (g == 2) ? Wc : Wo;
    const float* src = Wg + ((size_t)l * 2048 + k8 * 8) * 1024 + unit;
    bf16x8 v;
#pragma unroll
    for (int j = 0; j < 8; ++j) v[j] = (__bf16)src[(size_t)j * 1024];
    size_t slab = ((size_t)l * 128 + cb) * 131072;
    unsigned off = ((unsigned)(col * 4096 + k8 * 16)) ^ (unsigned)((col & 7) << 4);
    *(bf16x8*)((char*)Wperm + slab + off) = v;
}

// x[b][t][k] fp32 -> seq[t][b][k] bf16
__global__ void convX(const float* __restrict__ x, __bf16* __restrict__ seq) {
    int gid = blockIdx.x * 256 + threadIdx.x;      // 2,097,152
    int k8 = gid & 127;
    int b  = (gid >> 7) & 63;
    int t  = gid >> 13;
    const float* src = x + ((size_t)b * Tn + t) * Hn + k8 * 8;
    bf16x8 v;
#pragma unroll
    for (int j = 0; j < 8; ++j) v[j] = (__bf16)src[j];
    *(bf16x8*)(seq + (size_t)gid * 8) = v;
}

// ---------------------------------------------------------------------------
// Persistent kernel. 256 blocks x 512 threads, 1 block/CU.
// bid: rb = bid&1 (batch half, 32 rows), cb = bid>>1 (8 units = 32 gate cols).
// waves: kg = w&3 (512-wide K slice), mg = w>>2 (16 batch rows).
// LDS: [0,131072) swizzled weight slab; [131072,149504) zp reduction buffer.
__global__ __launch_bounds__(512, 2) void lstm_all(
    __bf16* __restrict__ seqA, __bf16* __restrict__ seqB,
    const __bf16* __restrict__ Wperm,
    const float* __restrict__ bip, const float* __restrict__ bfp,
    const float* __restrict__ bcp, const float* __restrict__ bop,
    unsigned* __restrict__ bar) {
    extern __shared__ char smem[];
    float* zp = (float*)(smem + 131072);           // [4][32][36]

    const int tid  = threadIdx.x;
    const int bid  = blockIdx.x;
    const int rb   = bid & 1;
    const int cb   = bid >> 1;
    const int w    = tid >> 6;
    const int lane = tid & 63;
    const int kg   = w & 3;
    const int mg   = w >> 2;
    const int l15  = lane & 15;
    const int lhi  = lane >> 4;
    const int arow = rb * 32 + mg * 16 + l15;      // batch row for A-frags
    const int ep_uu = tid & 7, ep_b = tid >> 3;    // epilogue map (tid<256)

    // B-fragment LDS addressing (see convW): hi bits disjoint from off bits.
    const int colA = 16 * 0 + l15, colB = 16 * 1 + l15;
    const unsigned sxor = (unsigned)((l15 & 7) << 4);
    const unsigned hiA = colA * 4096 + kg * 512;   // x-part window
    const unsigned hiB = colB * 4096 + kg * 512;

    unsigned* myflag = bar + (rb * 128 + cb) * 32; // own slot, 128 B stride
    unsigned* pollp  = bar + (rb * 128 + (tid & 127)) * 32;

    __bf16* inp  = seqA;
    __bf16* outp = seqB;
    const f32x4 vzero = {};

    for (int l = 0; l < 5; ++l) {
        // ---- stage this layer's 128 KiB weight slab into LDS (pre-swizzled)
        {
            const char* Wl = (const char*)Wperm + (((size_t)l * 128 + cb) * 131072);
#pragma unroll
            for (int it = 0; it < 16; ++it) {
                int off = it * 8192 + tid * 16;
                *(bf16x8*)(smem + off) = *(const bf16x8*)(Wl + off);
            }
        }
        // ---- per-layer epilogue constants + cell state (registers)
        float bia0 = 0.f, bia1 = 0.f, bia2 = 0.f, bia3 = 0.f, creg = 0.f;
        if (tid < 256) {
            int unit = cb * 8 + ep_uu;
            bia0 = bip[l * 1024 + unit];
            bia1 = bfp[l * 1024 + unit];
            bia2 = bcp[l * 1024 + unit];
            bia3 = bop[l * 1024 + unit];
        }
        __syncthreads();                           // weights staged

        f32x4 acc[2];
        acc[0] = vzero; acc[1] = vzero;
        {   // x-part for t = 0
            const __bf16* ax = inp + (size_t)arow * Hn + kg * 256 + lhi * 8;
#pragma unroll
            for (int kt = 0; kt < 8; ++kt) {
                unsigned o = (unsigned)((lhi << 4) | (kt << 6)) ^ sxor;
                bf16x8 a  = *(const bf16x8*)(ax + kt * 32);
                bf16x8 b0 = *(const bf16x8*)(smem + hiA + o);
                bf16x8 b1 = *(const bf16x8*)(smem + hiB + o);
                acc[0] = MFMA16(a, b0, acc[0]);
                acc[1] = MFMA16(a, b1, acc[1]);
            }
        }

        for (int t = 0; t < Tn; ++t) {
            if (t > 0) {
                // ---- wait: all 128 producer flags of our half at step l*256+t
                unsigned target = (unsigned)(l * Tn + t);
                if (tid < 128) {
                    while (__hip_atomic_load(pollp, __ATOMIC_RELAXED,
                                             __HIP_MEMORY_SCOPE_AGENT) < target)
                        __builtin_amdgcn_s_sleep(1);
                    __threadfence();               // acquire: inv caches
                }
                __syncthreads();
                // ---- h-part GEMM for step t
                const __bf16* ah = outp + ((size_t)(t - 1) * Bn + arow) * Hn
                                        + kg * 256 + lhi * 8;
#pragma unroll
                for (int kt = 0; kt < 8; ++kt) {
                    unsigned o = (unsigned)((lhi << 4) | (kt << 6)) ^ sxor;
                    bf16x8 a  = *(const bf16x8*)(ah + kt * 32);
                    bf16x8 b0 = *(const bf16x8*)(smem + hiA + 2048 + o);
                    bf16x8 b1 = *(const bf16x8*)(smem + hiB + 2048 + o);
                    acc[0] = MFMA16(a, b0, acc[0]);
                    acc[1] = MFMA16(a, b1, acc[1]);
                }
            }
            // ---- publish partials (D row = 4*lhi+j, col = 16*nf+l15)
#pragma unroll
            for (int nf = 0; nf < 2; ++nf)
#pragma unroll
                for (int j = 0; j < 4; ++j)
                    zp[(kg * 32 + mg * 16 + 4 * lhi + j) * 36 + 16 * nf + l15] =
                        acc[nf][j];
            __syncthreads();
            // ---- reduce + gates + state update (waves 0-3)
            if (tid < 256) {
                float z0 = bia0, z1 = bia1, z2 = bia2, z3 = bia3;
#pragma unroll
                for (int k2 = 0; k2 < 4; ++k2) {
                    const float* zr = zp + k2 * 1152 + ep_b * 36 + ep_uu;
                    z0 += zr[0]; z1 += zr[8]; z2 += zr[16]; z3 += zr[24];
                }
                float ii = 1.f / (1.f + expf(-z0));
                float ff = 1.f / (1.f + expf(-z1));
                float gg = tanhf(z2);
                float oo = 1.f / (1.f + expf(-z3));
                creg = creg * ff + ii * gg;
                float hv = oo * tanhf(creg);
                outp[((size_t)t * Bn + rb * 32 + ep_b) * Hn + cb * 8 + ep_uu] =
                    (__bf16)hv;
            }
            __syncthreads();                       // h stores drained to L2
            // ---- arrive: release our slot (no RMW contention)
            if (tid == 0) {
                __threadfence();                   // push L2 to coherence point
                __hip_atomic_store(myflag, (unsigned)(l * Tn + t + 1),
                                   __ATOMIC_RELAXED, __HIP_MEMORY_SCOPE_AGENT);
            }
            // ---- x-part GEMM for t+1 (h-independent -> hides flag latency)
            acc[0] = vzero; acc[1] = vzero;
            if (t < Tn - 1) {
                const __bf16* ax = inp + ((size_t)(t + 1) * Bn + arow) * Hn
                                       + kg * 256 + lhi * 8;
#pragma unroll
                for (int kt = 0; kt < 8; ++kt) {
                    unsigned o = (unsigned)((lhi << 4) | (kt << 6)) ^ sxor;
                    bf16x8 a  = *(const bf16x8*)(ax + kt * 32);
                    bf16x8 b0 = *(const bf16x8*)(smem + hiA + o);
                    bf16x8 b1 = *(const bf16x8*)(smem + hiB + o);
                    acc[0] = MFMA16(a, b0, acc[0]);
                    acc[1] = MFMA16(a, b1, acc[1]);
                }
            }
        }
        __bf16* tmp = outp; outp = inp; inp = tmp; // ping-pong
    }
}

// ---------------------------------------------------------------------------
// out[b] = dot(h5[T-1][b][:], Wfc) + bfc
__global__ void fc_kernel(const __bf16* __restrict__ seq, const float* __restrict__ Wfc,
                          const float* __restrict__ bfc, float* __restrict__ out) {
    int b = blockIdx.x;
    int tid = threadIdx.x;
    const __bf16* h = seq + ((size_t)(Tn - 1) * Bn + b) * Hn;
    float s = 0.f;
    for (int k = tid; k < Hn; k += 256) s += (float)h[k] * Wfc[k];
#pragma unroll
    for (int off = 32; off > 0; off >>= 1) s += __shfl_down(s, off);
    __shared__ float red[4];
    if ((tid & 63) == 0) red[tid >> 6] = s;
    __syncthreads();
    if (tid == 0) out[b] = red[0] + red[1] + red[2] + red[3] + bfc[0];
}

// ---------------------------------------------------------------------------
extern "C" void kernel_launch(void* const* d_in, const int* in_sizes, int n_in,
                              void* d_out, int out_size, void* d_ws, size_t ws_size,
                              hipStream_t stream) {
    const float* x   = (const float*)d_in[0];
    const float* Wi  = (const float*)d_in[1];
    const float* bi  = (const float*)d_in[2];
    const float* Wf  = (const float*)d_in[3];
    const float* bf  = (const float*)d_in[4];
    const float* Wc  = (const float*)d_in[5];
    const float* bc  = (const float*)d_in[6];
    const float* Wo  = (const float*)d_in[7];
    const float* bo  = (const float*)d_in[8];
    const float* Wfc = (const float*)d_in[9];
    const float* bfc = (const float*)d_in[10];

    char* ws = (char*)d_ws;
    __bf16*   Wperm = (__bf16*)ws;                                 // 83,886,080 B
    __bf16*   seqA  = (__bf16*)(ws + 83886080);                    // 33,554,432 B
    __bf16*   seqB  = (__bf16*)(ws + 83886080 + 33554432);         // 33,554,432 B
    unsigned* bar   = (unsigned*)(ws + 83886080 + 2 * 33554432);   //     32,768 B

    static int lds_attr_set = -1;
    (void)lds_attr_set;
    hipFuncSetAttribute((const void*)lstm_all,
                        hipFuncAttributeMaxDynamicSharedMemorySize, 149504);

    hipLaunchKernelGGL(convW, dim3(20480), dim3(256), 0, stream, Wi, Wf, Wc, Wo, Wperm);
    hipLaunchKernelGGL(convX, dim3(8192), dim3(256), 0, stream, x, seqA);
    hipMemsetAsync(bar, 0, 32768, stream);

    void* args[] = {(void*)&seqA, (void*)&seqB, (void*)&Wperm,
                    (void*)&bi, (void*)&bf, (void*)&bc, (void*)&bo, (void*)&bar};
    hipLaunchCooperativeKernel((const void*)lstm_all, dim3(256), dim3(512),
                               args, 149504, stream);

    // after 5 ping-pongs the final hidden sequence is in seqB
    hipLaunchKernelGGL(fc_kernel, dim3(64), dim3(256), 0, stream, seqB, Wfc, bfc,
                       (float*)d_out);
}

// Round 4
// 7186.702 us; speedup vs baseline: 3.4056x; 3.3513x over previous
//
#include <hip/hip_runtime.h>
#include <hip/hip_bf16.h>

// 5-layer LSTM, B=64, T=256, H=1024. bf16 MFMA (16x16x32), fp32 state.
// Round 4: persistent cooperative kernel; NO per-step cache-wide fences.
//  - h exchange via targeted sc0/sc1 (coherent, L2-bypass) loads/stores
//  - flag-array barrier polled with sc1 loads; one acquire fence per LAYER
//  - weights in LDS in fragment-linear layout (conflict-free ds_read_b128)
//  - h-part B-fragments held in VGPRs; x-part read from LDS per step

using bf16x8 = __attribute__((ext_vector_type(8))) __bf16;
using f32x4  = __attribute__((ext_vector_type(4))) float;

#define Tn 256
#define Bn 64
#define Hn 1024

#define MFMA16(a, b, c) __builtin_amdgcn_mfma_f32_16x16x32_bf16((a), (b), (c), 0, 0, 0)

// ---------------------------------------------------------------------------
// Wg[l][k][unit] fp32 -> Wperm fragment-linear bf16:
// per (l,cb) a 128 KiB slab of 128 fragments x 64 lanes x 16 B.
// frag = ((p*4+kg)*8+kt)*2+nf  (p: 0=x,1=h; kg=K-window; kt; nf=col-half)
// lane = lhi*16 + l15; element (col=nf*16+l15, k=p*1024+kg*256+kt*32+lhi*8+j)
__global__ void convW(const float* __restrict__ Wi, const float* __restrict__ Wf,
                      const float* __restrict__ Wc, const float* __restrict__ Wo,
                      __bf16* __restrict__ Wperm) {
    int gid = blockIdx.x * 256 + threadIdx.x;      // 5*128*32*256 = 5,242,880
    int k8  = gid & 255;                           // 8-k chunk: k = k8*8
    int col = (gid >> 8) & 31;
    int cb  = (gid >> 13) & 127;
    int l   = gid >> 20;
    int g   = col >> 3;
    int uu  = col & 7;
    int unit = cb * 8 + uu;
    const float* Wg = (g == 0) ? Wi : (g == 1) ? Wf : (g == 2) ? Wc : Wo;
    const float* src = Wg + ((size_t)l * 2048 + k8 * 8) * 1024 + unit;
    bf16x8 v;
#pragma unroll
    for (int j = 0; j < 8; ++j) v[j] = (__bf16)src[(size_t)j * 1024];
    int p   = k8 >> 7;
    int kg  = (k8 >> 5) & 3;
    int kt  = (k8 >> 2) & 7;
    int lh  = k8 & 3;
    int nf  = col >> 4;
    int l15 = col & 15;
    int frag = ((p * 4 + kg) * 8 + kt) * 2 + nf;
    int lane = lh * 16 + l15;
    size_t dst = ((size_t)l * 128 + cb) * 131072 + (size_t)frag * 1024 + lane * 16;
    *(bf16x8*)((char*)Wperm + dst) = v;
}

// x[b][t][k] fp32 -> seq[t][b][k] bf16
__global__ void convX(const float* __restrict__ x, __bf16* __restrict__ seq) {
    int gid = blockIdx.x * 256 + threadIdx.x;      // 2,097,152
    int k8 = gid & 127;
    int b  = (gid >> 7) & 63;
    int t  = gid >> 13;
    const float* src = x + ((size_t)b * Tn + t) * Hn + k8 * 8;
    bf16x8 v;
#pragma unroll
    for (int j = 0; j < 8; ++j) v[j] = (__bf16)src[j];
    *(bf16x8*)(seq + (size_t)gid * 8) = v;
}

// ---------------------------------------------------------------------------
// Coherent (L2-bypass, L3-serviced) 8-fragment load: one A-row k-window.
__device__ __forceinline__ void load8_coh(const __bf16* p,
        bf16x8& a0, bf16x8& a1, bf16x8& a2, bf16x8& a3,
        bf16x8& a4, bf16x8& a5, bf16x8& a6, bf16x8& a7) {
    asm volatile(
        "global_load_dwordx4 %0, %8, off sc0 sc1\n\t"
        "global_load_dwordx4 %1, %8, off offset:64 sc0 sc1\n\t"
        "global_load_dwordx4 %2, %8, off offset:128 sc0 sc1\n\t"
        "global_load_dwordx4 %3, %8, off offset:192 sc0 sc1\n\t"
        "global_load_dwordx4 %4, %8, off offset:256 sc0 sc1\n\t"
        "global_load_dwordx4 %5, %8, off offset:320 sc0 sc1\n\t"
        "global_load_dwordx4 %6, %8, off offset:384 sc0 sc1\n\t"
        "global_load_dwordx4 %7, %8, off offset:448 sc0 sc1\n\t"
        "s_waitcnt vmcnt(0)"
        : "=&v"(a0), "=&v"(a1), "=&v"(a2), "=&v"(a3),
          "=&v"(a4), "=&v"(a5), "=&v"(a6), "=&v"(a7)
        : "v"(p) : "memory");
    __builtin_amdgcn_sched_barrier(0);
}

__device__ __forceinline__ void store_coh_u32(void* p, unsigned v) {
    asm volatile("global_store_dword %0, %1, off sc0 sc1" :: "v"(p), "v"(v) : "memory");
}

__device__ __forceinline__ unsigned load_coh_u32(const void* p) {
    unsigned v;
    asm volatile("global_load_dword %0, %1, off sc0 sc1\n\ts_waitcnt vmcnt(0)"
                 : "=v"(v) : "v"(p) : "memory");
    return v;
}

// ---------------------------------------------------------------------------
// Persistent kernel. 256 blocks x 512 threads, 1 block/CU.
// bid: rb = bid&1 (batch half, 32 rows), cb = bid>>1 (8 units = 32 gate cols).
// waves: kg = w&3 (K-window), mg = w>>2 (16 batch rows).
// LDS: [0,131072) weight slab (fragment-linear); [131072,149504) zp buffer.
__global__ __launch_bounds__(512, 2) void lstm_all(
    __bf16* __restrict__ seqA, __bf16* __restrict__ seqB,
    const __bf16* __restrict__ Wperm,
    const float* __restrict__ bip, const float* __restrict__ bfp,
    const float* __restrict__ bcp, const float* __restrict__ bop,
    unsigned* __restrict__ bar) {
    extern __shared__ char smem[];
    float* zp = (float*)(smem + 131072);           // [4][32][36]

    const int tid  = threadIdx.x;
    const int bid  = blockIdx.x;
    const int rb   = bid & 1;
    const int cb   = bid >> 1;
    const int lane = tid & 63;
    const int kg   = (tid >> 6) & 3;
    const int mg   = tid >> 8;
    const int l15  = lane & 15;
    const int lhi  = lane >> 4;
    const int arow = rb * 32 + mg * 16 + l15;      // batch row for A-frags
    const unsigned lane16 = (unsigned)lane << 4;

    unsigned* myflag = bar + ((size_t)rb * 128 + cb) * 32;
    const unsigned* pollp = bar + ((size_t)rb * 128 + (tid & 127)) * 32;

    __bf16* inp  = seqA;
    __bf16* outp = seqB;

    for (int l = 0; l < 5; ++l) {
        // one acquire per layer: invalidate L1/L2 so normal-cached x loads of
        // the (rewritten, ping-ponged) inp buffer can't hit stale lines.
        __builtin_amdgcn_fence(__ATOMIC_ACQUIRE, "agent");

        // ---- stage this layer's 128 KiB weight slab into LDS
        const char* Wl = (const char*)Wperm + ((size_t)l * 128 + cb) * 131072;
#pragma unroll
        for (int it = 0; it < 16; ++it) {
            int off = it * 8192 + tid * 16;
            *(bf16x8*)(smem + off) = *(const bf16x8*)(Wl + off);
        }
        // ---- per-layer epilogue constants + cell state (registers)
        float bia0 = 0.f, bia1 = 0.f, bia2 = 0.f, bia3 = 0.f, creg = 0.f;
        if (tid < 256) {
            int unit = cb * 8 + (tid & 7);
            bia0 = bip[l * 1024 + unit];
            bia1 = bfp[l * 1024 + unit];
            bia2 = bcp[l * 1024 + unit];
            bia3 = bop[l * 1024 + unit];
        }
        __syncthreads();                           // weights staged

        // ---- hold h-part B-fragments in registers (16 frags = 64 VGPR)
        bf16x8 bh[2][8];
#pragma unroll
        for (int nf = 0; nf < 2; ++nf)
#pragma unroll
            for (int kt = 0; kt < 8; ++kt)
                bh[nf][kt] = *(const bf16x8*)(smem +
                    ((unsigned)((((4 + kg) * 8 + kt) * 2 + nf) << 10)) + lane16);

        // ---- x-part GEMM for t = 0
        f32x4 acc0 = {}, acc1 = {};
        {
            const __bf16* ax = inp + (size_t)arow * Hn + kg * 256 + lhi * 8;
#pragma unroll
            for (int kt = 0; kt < 8; ++kt) {
                bf16x8 a  = *(const bf16x8*)(ax + kt * 32);
                bf16x8 b0 = *(const bf16x8*)(smem +
                    ((unsigned)(((kg * 8 + kt) * 2 + 0) << 10)) + lane16);
                bf16x8 b1 = *(const bf16x8*)(smem +
                    ((unsigned)(((kg * 8 + kt) * 2 + 1) << 10)) + lane16);
                acc0 = MFMA16(a, b0, acc0);
                acc1 = MFMA16(a, b1, acc1);
            }
        }

        for (int t = 0; t < Tn; ++t) {
            if (t > 0) {
                // ---- wait: all 128 producers of our half at step l*256+t
                unsigned target = (unsigned)(l * Tn + t);
                if (tid < 128) {
                    while (load_coh_u32(pollp) < target)
                        __builtin_amdgcn_s_sleep(1);
                }
                __syncthreads();
                // ---- h-part GEMM for step t (coherent A loads, reg B)
                bf16x8 a0, a1, a2, a3, a4, a5, a6, a7;
                load8_coh(outp + ((size_t)(t - 1) * Bn + arow) * Hn
                               + kg * 256 + lhi * 8,
                          a0, a1, a2, a3, a4, a5, a6, a7);
                acc0 = MFMA16(a0, bh[0][0], acc0); acc1 = MFMA16(a0, bh[1][0], acc1);
                acc0 = MFMA16(a1, bh[0][1], acc0); acc1 = MFMA16(a1, bh[1][1], acc1);
                acc0 = MFMA16(a2, bh[0][2], acc0); acc1 = MFMA16(a2, bh[1][2], acc1);
                acc0 = MFMA16(a3, bh[0][3], acc0); acc1 = MFMA16(a3, bh[1][3], acc1);
                acc0 = MFMA16(a4, bh[0][4], acc0); acc1 = MFMA16(a4, bh[1][4], acc1);
                acc0 = MFMA16(a5, bh[0][5], acc0); acc1 = MFMA16(a5, bh[1][5], acc1);
                acc0 = MFMA16(a6, bh[0][6], acc0); acc1 = MFMA16(a6, bh[1][6], acc1);
                acc0 = MFMA16(a7, bh[0][7], acc0); acc1 = MFMA16(a7, bh[1][7], acc1);
            }
            // ---- publish partials (D row = 4*lhi+j, col = 16*nf+l15)
#pragma unroll
            for (int j = 0; j < 4; ++j) {
                int row = kg * 32 + mg * 16 + 4 * lhi + j;
                zp[row * 36 + l15]      = acc0[j];
                zp[row * 36 + 16 + l15] = acc1[j];
            }
            __syncthreads();
            // ---- reduce + gates + state update + coherent h store
            if (tid < 256) {
                int uu = tid & 7, eb = tid >> 3;
                float z0 = bia0, z1 = bia1, z2 = bia2, z3 = bia3;
#pragma unroll
                for (int k2 = 0; k2 < 4; ++k2) {
                    const float* zr = zp + (k2 * 32 + eb) * 36 + uu;
                    z0 += zr[0]; z1 += zr[8]; z2 += zr[16]; z3 += zr[24];
                }
                float ii = 1.f / (1.f + expf(-z0));
                float ff = 1.f / (1.f + expf(-z1));
                float gg = tanhf(z2);
                float oo = 1.f / (1.f + expf(-z3));
                creg = creg * ff + ii * gg;
                float hv = oo * tanhf(creg);
                float hv2 = __shfl_xor(hv, 1);     // partner unit's value
                if (!(tid & 1)) {
                    unsigned lo = (unsigned)__builtin_bit_cast(unsigned short, (__bf16)hv);
                    unsigned hi = (unsigned)__builtin_bit_cast(unsigned short, (__bf16)hv2);
                    unsigned* dst = (unsigned*)(outp +
                        (((size_t)t * Bn + rb * 32 + eb) * Hn + cb * 8 + uu));
                    store_coh_u32(dst, lo | (hi << 16));
                }
            }
            asm volatile("s_waitcnt vmcnt(0)" ::: "memory");  // h at L3
            __syncthreads();
            // ---- arrive: release our flag (sc1, no cache-wide ops)
            if (tid == 0)
                store_coh_u32(myflag, (unsigned)(l * Tn + t + 1));
            // ---- x-part GEMM for t+1 (h-independent -> hides flag latency)
            acc0 = (f32x4){}; acc1 = (f32x4){};
            if (t < Tn - 1) {
                const __bf16* ax = inp + ((size_t)(t + 1) * Bn + arow) * Hn
                                       + kg * 256 + lhi * 8;
#pragma unroll
                for (int kt = 0; kt < 8; ++kt) {
                    bf16x8 a  = *(const bf16x8*)(ax + kt * 32);
                    bf16x8 b0 = *(const bf16x8*)(smem +
                        ((unsigned)(((kg * 8 + kt) * 2 + 0) << 10)) + lane16);
                    bf16x8 b1 = *(const bf16x8*)(smem +
                        ((unsigned)(((kg * 8 + kt) * 2 + 1) << 10)) + lane16);
                    acc0 = MFMA16(a, b0, acc0);
                    acc1 = MFMA16(a, b1, acc1);
                }
            }
        }
        __bf16* tmp = outp; outp = inp; inp = tmp; // ping-pong
    }
}

// ---------------------------------------------------------------------------
// out[b] = dot(h5[T-1][b][:], Wfc) + bfc
__global__ void fc_kernel(const __bf16* __restrict__ seq, const float* __restrict__ Wfc,
                          const float* __restrict__ bfc, float* __restrict__ out) {
    int b = blockIdx.x;
    int tid = threadIdx.x;
    const __bf16* h = seq + ((size_t)(Tn - 1) * Bn + b) * Hn;
    float s = 0.f;
    for (int k = tid; k < Hn; k += 256) s += (float)h[k] * Wfc[k];
#pragma unroll
    for (int off = 32; off > 0; off >>= 1) s += __shfl_down(s, off);
    __shared__ float red[4];
    if ((tid & 63) == 0) red[tid >> 6] = s;
    __syncthreads();
    if (tid == 0) out[b] = red[0] + red[1] + red[2] + red[3] + bfc[0];
}

// ---------------------------------------------------------------------------
extern "C" void kernel_launch(void* const* d_in, const int* in_sizes, int n_in,
                              void* d_out, int out_size, void* d_ws, size_t ws_size,
                              hipStream_t stream) {
    const float* x   = (const float*)d_in[0];
    const float* Wi  = (const float*)d_in[1];
    const float* bi  = (const float*)d_in[2];
    const float* Wf  = (const float*)d_in[3];
    const float* bf  = (const float*)d_in[4];
    const float* Wc  = (const float*)d_in[5];
    const float* bc  = (const float*)d_in[6];
    const float* Wo  = (const float*)d_in[7];
    const float* bo  = (const float*)d_in[8];
    const float* Wfc = (const float*)d_in[9];
    const float* bfc = (const float*)d_in[10];

    char* ws = (char*)d_ws;
    __bf16*   Wperm = (__bf16*)ws;                                 // 83,886,080 B
    __bf16*   seqA  = (__bf16*)(ws + 83886080);                    // 33,554,432 B
    __bf16*   seqB  = (__bf16*)(ws + 83886080 + 33554432);         // 33,554,432 B
    unsigned* bar   = (unsigned*)(ws + 83886080 + 2 * 33554432);   //     32,768 B

    hipFuncSetAttribute((const void*)lstm_all,
                        hipFuncAttributeMaxDynamicSharedMemorySize, 149504);

    hipLaunchKernelGGL(convW, dim3(20480), dim3(256), 0, stream, Wi, Wf, Wc, Wo, Wperm);
    hipLaunchKernelGGL(convX, dim3(8192), dim3(256), 0, stream, x, seqA);
    hipMemsetAsync(bar, 0, 32768, stream);

    void* args[] = {(void*)&seqA, (void*)&seqB, (void*)&Wperm,
                    (void*)&bi, (void*)&bf, (void*)&bc, (void*)&bo, (void*)&bar};
    hipLaunchCooperativeKernel((const void*)lstm_all, dim3(256), dim3(512),
                               args, 149504, stream);

    // after 5 ping-pongs the final hidden sequence is in seqB
    hipLaunchKernelGGL(fc_kernel, dim3(64), dim3(256), 0, stream, seqB, Wfc, bfc,
                       (float*)d_out);
}

// Round 5
// 6690.689 us; speedup vs baseline: 3.6581x; 1.0741x over previous
//
#include <hip/hip_runtime.h>
#include <hip/hip_bf16.h>

// 5-layer LSTM, B=64, T=256, H=1024. bf16 MFMA (16x16x32), fp32 state.
// Round 5: r4 protocol (sc0/sc1 targeted coherence, no cache-wide fences) +
//  - per-WAVE flag wait: wave kg polls only its 32 producers, no barrier
//    between wait and h-GEMM (straggler set 128 -> 32, 3 -> 2 barriers/step)
//  - hardware transcendentals (v_exp_f32 / v_rcp_f32) in the epilogue
//  - hard spin polling (no s_sleep)

using bf16x8 = __attribute__((ext_vector_type(8))) __bf16;
using f32x4  = __attribute__((ext_vector_type(4))) float;

#define Tn 256
#define Bn 64
#define Hn 1024

#define MFMA16(a, b, c) __builtin_amdgcn_mfma_f32_16x16x32_bf16((a), (b), (c), 0, 0, 0)

// ---------------------------------------------------------------------------
// Wg[l][k][unit] fp32 -> Wperm fragment-linear bf16:
// per (l,cb) a 128 KiB slab of 128 fragments x 64 lanes x 16 B.
// frag = ((p*4+kg)*8+kt)*2+nf  (p: 0=x,1=h; kg=K-window; kt; nf=col-half)
// lane = lhi*16 + l15; element (col=nf*16+l15, k=p*1024+kg*256+kt*32+lhi*8+j)
__global__ void convW(const float* __restrict__ Wi, const float* __restrict__ Wf,
                      const float* __restrict__ Wc, const float* __restrict__ Wo,
                      __bf16* __restrict__ Wperm) {
    int gid = blockIdx.x * 256 + threadIdx.x;      // 5*128*32*256 = 5,242,880
    int k8  = gid & 255;                           // 8-k chunk: k = k8*8
    int col = (gid >> 8) & 31;
    int cb  = (gid >> 13) & 127;
    int l   = gid >> 20;
    int g   = col >> 3;
    int uu  = col & 7;
    int unit = cb * 8 + uu;
    const float* Wg = (g == 0) ? Wi : (g == 1) ? Wf : (g == 2) ? Wc : Wo;
    const float* src = Wg + ((size_t)l * 2048 + k8 * 8) * 1024 + unit;
    bf16x8 v;
#pragma unroll
    for (int j = 0; j < 8; ++j) v[j] = (__bf16)src[(size_t)j * 1024];
    int p   = k8 >> 7;
    int kg  = (k8 >> 5) & 3;
    int kt  = (k8 >> 2) & 7;
    int lh  = k8 & 3;
    int nf  = col >> 4;
    int l15 = col & 15;
    int frag = ((p * 4 + kg) * 8 + kt) * 2 + nf;
    int lane = lh * 16 + l15;
    size_t dst = ((size_t)l * 128 + cb) * 131072 + (size_t)frag * 1024 + lane * 16;
    *(bf16x8*)((char*)Wperm + dst) = v;
}

// x[b][t][k] fp32 -> seq[t][b][k] bf16
__global__ void convX(const float* __restrict__ x, __bf16* __restrict__ seq) {
    int gid = blockIdx.x * 256 + threadIdx.x;      // 2,097,152
    int k8 = gid & 127;
    int b  = (gid >> 7) & 63;
    int t  = gid >> 13;
    const float* src = x + ((size_t)b * Tn + t) * Hn + k8 * 8;
    bf16x8 v;
#pragma unroll
    for (int j = 0; j < 8; ++j) v[j] = (__bf16)src[j];
    *(bf16x8*)(seq + (size_t)gid * 8) = v;
}

// ---------------------------------------------------------------------------
// Coherent (L2-bypass, L3-serviced) 8-fragment load: one A-row k-window.
__device__ __forceinline__ void load8_coh(const __bf16* p,
        bf16x8& a0, bf16x8& a1, bf16x8& a2, bf16x8& a3,
        bf16x8& a4, bf16x8& a5, bf16x8& a6, bf16x8& a7) {
    asm volatile(
        "global_load_dwordx4 %0, %8, off sc0 sc1\n\t"
        "global_load_dwordx4 %1, %8, off offset:64 sc0 sc1\n\t"
        "global_load_dwordx4 %2, %8, off offset:128 sc0 sc1\n\t"
        "global_load_dwordx4 %3, %8, off offset:192 sc0 sc1\n\t"
        "global_load_dwordx4 %4, %8, off offset:256 sc0 sc1\n\t"
        "global_load_dwordx4 %5, %8, off offset:320 sc0 sc1\n\t"
        "global_load_dwordx4 %6, %8, off offset:384 sc0 sc1\n\t"
        "global_load_dwordx4 %7, %8, off offset:448 sc0 sc1\n\t"
        "s_waitcnt vmcnt(0)"
        : "=&v"(a0), "=&v"(a1), "=&v"(a2), "=&v"(a3),
          "=&v"(a4), "=&v"(a5), "=&v"(a6), "=&v"(a7)
        : "v"(p) : "memory");
    __builtin_amdgcn_sched_barrier(0);
}

__device__ __forceinline__ void store_coh_u32(void* p, unsigned v) {
    asm volatile("global_store_dword %0, %1, off sc0 sc1" :: "v"(p), "v"(v) : "memory");
}

__device__ __forceinline__ unsigned load_coh_u32(const void* p) {
    unsigned v;
    asm volatile("global_load_dword %0, %1, off sc0 sc1\n\ts_waitcnt vmcnt(0)"
                 : "=v"(v) : "v"(p) : "memory");
    return v;
}

// fast gates: v_exp_f32 computes 2^x; v_rcp_f32 ~1ulp
__device__ __forceinline__ float fsigmoid(float z) {
    return __builtin_amdgcn_rcpf(1.f + __builtin_amdgcn_exp2f(-1.44269504089f * z));
}
__device__ __forceinline__ float ftanh(float z) {
    return 1.f - 2.f * __builtin_amdgcn_rcpf(1.f + __builtin_amdgcn_exp2f(2.88539008178f * z));
}

// ---------------------------------------------------------------------------
// Persistent kernel. 256 blocks x 512 threads, 1 block/CU.
// bid: rb = bid&1 (batch half, 32 rows), cb = bid>>1 (8 units = 32 gate cols).
// waves: kg = w&3 (K-window), mg = w>>2 (16 batch rows).
// Wave kg's h-part needs h-units [kg*256, kg*256+256) = producers
// cb in [kg*32, kg*32+32): poll exactly those 32 flags, lane-parallel.
// LDS: [0,131072) weight slab (fragment-linear); [131072,149504) zp buffer.
__global__ __launch_bounds__(512, 2) void lstm_all(
    __bf16* __restrict__ seqA, __bf16* __restrict__ seqB,
    const __bf16* __restrict__ Wperm,
    const float* __restrict__ bip, const float* __restrict__ bfp,
    const float* __restrict__ bcp, const float* __restrict__ bop,
    unsigned* __restrict__ bar) {
    extern __shared__ char smem[];
    float* zp = (float*)(smem + 131072);           // [4][32][36]

    const int tid  = threadIdx.x;
    const int bid  = blockIdx.x;
    const int rb   = bid & 1;
    const int cb   = bid >> 1;
    const int lane = tid & 63;
    const int kg   = (tid >> 6) & 3;
    const int mg   = tid >> 8;
    const int l15  = lane & 15;
    const int lhi  = lane >> 4;
    const int arow = rb * 32 + mg * 16 + l15;      // batch row for A-frags
    const unsigned lane16 = (unsigned)lane << 4;

    unsigned* myflag = bar + ((size_t)rb * 128 + cb) * 32;
    const unsigned* wflag = bar + ((size_t)rb * 128 + kg * 32 + (lane & 31)) * 32;

    __bf16* inp  = seqA;
    __bf16* outp = seqB;

    for (int l = 0; l < 5; ++l) {
        // one acquire per layer: inv L1/L2 so normal-cached x loads of the
        // ping-ponged inp buffer can't hit stale lines.
        __builtin_amdgcn_fence(__ATOMIC_ACQUIRE, "agent");

        // ---- stage this layer's 128 KiB weight slab into LDS
        const char* Wl = (const char*)Wperm + ((size_t)l * 128 + cb) * 131072;
#pragma unroll
        for (int it = 0; it < 16; ++it) {
            int off = it * 8192 + tid * 16;
            *(bf16x8*)(smem + off) = *(const bf16x8*)(Wl + off);
        }
        // ---- per-layer epilogue constants + cell state (registers)
        float bia0 = 0.f, bia1 = 0.f, bia2 = 0.f, bia3 = 0.f, creg = 0.f;
        if (tid < 256) {
            int unit = cb * 8 + (tid & 7);
            bia0 = bip[l * 1024 + unit];
            bia1 = bfp[l * 1024 + unit];
            bia2 = bcp[l * 1024 + unit];
            bia3 = bop[l * 1024 + unit];
        }
        __syncthreads();                           // weights staged

        // ---- hold h-part B-fragments in registers (16 frags = 64 VGPR)
        bf16x8 bh[2][8];
#pragma unroll
        for (int nf = 0; nf < 2; ++nf)
#pragma unroll
            for (int kt = 0; kt < 8; ++kt)
                bh[nf][kt] = *(const bf16x8*)(smem +
                    ((unsigned)((((4 + kg) * 8 + kt) * 2 + nf) << 10)) + lane16);

        // ---- x-part GEMM for t = 0
        f32x4 acc0 = {}, acc1 = {};
        {
            const __bf16* ax = inp + (size_t)arow * Hn + kg * 256 + lhi * 8;
#pragma unroll
            for (int kt = 0; kt < 8; ++kt) {
                bf16x8 a  = *(const bf16x8*)(ax + kt * 32);
                bf16x8 b0 = *(const bf16x8*)(smem +
                    ((unsigned)(((kg * 8 + kt) * 2 + 0) << 10)) + lane16);
                bf16x8 b1 = *(const bf16x8*)(smem +
                    ((unsigned)(((kg * 8 + kt) * 2 + 1) << 10)) + lane16);
                acc0 = MFMA16(a, b0, acc0);
                acc1 = MFMA16(a, b1, acc1);
            }
        }

        for (int t = 0; t < Tn; ++t) {
            if (t > 0) {
                // ---- per-wave wait: only OUR 32 producers at step l*256+t
                unsigned target = (unsigned)(l * Tn + t);
                while (true) {
                    unsigned v = load_coh_u32(wflag);
                    if (__all((int)(v >= target))) break;
                }
                // ---- h-part GEMM for step t (coherent A loads, reg B)
                bf16x8 a0, a1, a2, a3, a4, a5, a6, a7;
                load8_coh(outp + ((size_t)(t - 1) * Bn + arow) * Hn
                               + kg * 256 + lhi * 8,
                          a0, a1, a2, a3, a4, a5, a6, a7);
                acc0 = MFMA16(a0, bh[0][0], acc0); acc1 = MFMA16(a0, bh[1][0], acc1);
                acc0 = MFMA16(a1, bh[0][1], acc0); acc1 = MFMA16(a1, bh[1][1], acc1);
                acc0 = MFMA16(a2, bh[0][2], acc0); acc1 = MFMA16(a2, bh[1][2], acc1);
                acc0 = MFMA16(a3, bh[0][3], acc0); acc1 = MFMA16(a3, bh[1][3], acc1);
                acc0 = MFMA16(a4, bh[0][4], acc0); acc1 = MFMA16(a4, bh[1][4], acc1);
                acc0 = MFMA16(a5, bh[0][5], acc0); acc1 = MFMA16(a5, bh[1][5], acc1);
                acc0 = MFMA16(a6, bh[0][6], acc0); acc1 = MFMA16(a6, bh[1][6], acc1);
                acc0 = MFMA16(a7, bh[0][7], acc0); acc1 = MFMA16(a7, bh[1][7], acc1);
            }
            // ---- publish partials (D row = 4*lhi+j, col = 16*nf+l15)
#pragma unroll
            for (int j = 0; j < 4; ++j) {
                int row = kg * 32 + mg * 16 + 4 * lhi + j;
                zp[row * 36 + l15]      = acc0[j];
                zp[row * 36 + 16 + l15] = acc1[j];
            }
            __syncthreads();
            // ---- reduce + gates + state update + coherent h store
            if (tid < 256) {
                int uu = tid & 7, eb = tid >> 3;
                float z0 = bia0, z1 = bia1, z2 = bia2, z3 = bia3;
#pragma unroll
                for (int k2 = 0; k2 < 4; ++k2) {
                    const float* zr = zp + (k2 * 32 + eb) * 36 + uu;
                    z0 += zr[0]; z1 += zr[8]; z2 += zr[16]; z3 += zr[24];
                }
                float ii = fsigmoid(z0);
                float ff = fsigmoid(z1);
                float gg = ftanh(z2);
                float oo = fsigmoid(z3);
                creg = creg * ff + ii * gg;
                float hv = oo * ftanh(creg);
                float hv2 = __shfl_xor(hv, 1);     // partner unit's value
                if (!(tid & 1)) {
                    unsigned lo = (unsigned)__builtin_bit_cast(unsigned short, (__bf16)hv);
                    unsigned hi = (unsigned)__builtin_bit_cast(unsigned short, (__bf16)hv2);
                    unsigned* dst = (unsigned*)(outp +
                        (((size_t)t * Bn + rb * 32 + eb) * Hn + cb * 8 + uu));
                    store_coh_u32(dst, lo | (hi << 16));
                }
            }
            asm volatile("s_waitcnt vmcnt(0)" ::: "memory");  // h at L3
            __syncthreads();
            // ---- arrive: release our flag (sc1, no cache-wide ops)
            if (tid == 0)
                store_coh_u32(myflag, (unsigned)(l * Tn + t + 1));
            // ---- x-part GEMM for t+1 (h-independent -> hides flag latency)
            acc0 = (f32x4){}; acc1 = (f32x4){};
            if (t < Tn - 1) {
                const __bf16* ax = inp + ((size_t)(t + 1) * Bn + arow) * Hn
                                       + kg * 256 + lhi * 8;
#pragma unroll
                for (int kt = 0; kt < 8; ++kt) {
                    bf16x8 a  = *(const bf16x8*)(ax + kt * 32);
                    bf16x8 b0 = *(const bf16x8*)(smem +
                        ((unsigned)(((kg * 8 + kt) * 2 + 0) << 10)) + lane16);
                    bf16x8 b1 = *(const bf16x8*)(smem +
                        ((unsigned)(((kg * 8 + kt) * 2 + 1) << 10)) + lane16);
                    acc0 = MFMA16(a, b0, acc0);
                    acc1 = MFMA16(a, b1, acc1);
                }
            }
        }
        __bf16* tmp = outp; outp = inp; inp = tmp; // ping-pong
    }
}

// ---------------------------------------------------------------------------
// out[b] = dot(h5[T-1][b][:], Wfc) + bfc
__global__ void fc_kernel(const __bf16* __restrict__ seq, const float* __restrict__ Wfc,
                          const float* __restrict__ bfc, float* __restrict__ out) {
    int b = blockIdx.x;
    int tid = threadIdx.x;
    const __bf16* h = seq + ((size_t)(Tn - 1) * Bn + b) * Hn;
    float s = 0.f;
    for (int k = tid; k < Hn; k += 256) s += (float)h[k] * Wfc[k];
#pragma unroll
    for (int off = 32; off > 0; off >>= 1) s += __shfl_down(s, off);
    __shared__ float red[4];
    if ((tid & 63) == 0) red[tid >> 6] = s;
    __syncthreads();
    if (tid == 0) out[b] = red[0] + red[1] + red[2] + red[3] + bfc[0];
}

// ---------------------------------------------------------------------------
extern "C" void kernel_launch(void* const* d_in, const int* in_sizes, int n_in,
                              void* d_out, int out_size, void* d_ws, size_t ws_size,
                              hipStream_t stream) {
    const float* x   = (const float*)d_in[0];
    const float* Wi  = (const float*)d_in[1];
    const float* bi  = (const float*)d_in[2];
    const float* Wf  = (const float*)d_in[3];
    const float* bf  = (const float*)d_in[4];
    const float* Wc  = (const float*)d_in[5];
    const float* bc  = (const float*)d_in[6];
    const float* Wo  = (const float*)d_in[7];
    const float* bo  = (const float*)d_in[8];
    const float* Wfc = (const float*)d_in[9];
    const float* bfc = (const float*)d_in[10];

    char* ws = (char*)d_ws;
    __bf16*   Wperm = (__bf16*)ws;                                 // 83,886,080 B
    __bf16*   seqA  = (__bf16*)(ws + 83886080);                    // 33,554,432 B
    __bf16*   seqB  = (__bf16*)(ws + 83886080 + 33554432);         // 33,554,432 B
    unsigned* bar   = (unsigned*)(ws + 83886080 + 2 * 33554432);   //     32,768 B

    hipFuncSetAttribute((const void*)lstm_all,
                        hipFuncAttributeMaxDynamicSharedMemorySize, 149504);

    hipLaunchKernelGGL(convW, dim3(20480), dim3(256), 0, stream, Wi, Wf, Wc, Wo, Wperm);
    hipLaunchKernelGGL(convX, dim3(8192), dim3(256), 0, stream, x, seqA);
    hipMemsetAsync(bar, 0, 32768, stream);

    void* args[] = {(void*)&seqA, (void*)&seqB, (void*)&Wperm,
                    (void*)&bi, (void*)&bf, (void*)&bc, (void*)&bo, (void*)&bar};
    hipLaunchCooperativeKernel((const void*)lstm_all, dim3(256), dim3(512),
                               args, 149504, stream);

    // after 5 ping-pongs the final hidden sequence is in seqB
    hipLaunchKernelGGL(fc_kernel, dim3(64), dim3(256), 0, stream, seqB, Wfc, bfc,
                       (float*)d_out);
}

// Round 6
// 6051.409 us; speedup vs baseline: 4.0445x; 1.1056x over previous
//
#include <hip/hip_runtime.h>
#include <hip/hip_bf16.h>

// 5-layer LSTM, B=64, T=256, H=1024. bf16 MFMA (16x16x32), fp32 state.
// Round 6: r5 protocol, minus its two confirmed costs:
//  - h exchange read via NORMAL CACHED loads (L2-shared broadcast; first
//    touch of any outp[t] line is post-flag => fresh fill; per-layer acquire
//    fence kills cross-layer staleness; sc0sc1 stores keep L3 authoritative)
//  - per-WAVE producer flags after per-wave vmcnt drain (no post-store
//    __syncthreads); consumers poll 64 packed flags, 1 dword/lane
//  - h-stores packed to dwordx4 via shfl tree (32 stores/block vs 128)

using bf16x8 = __attribute__((ext_vector_type(8))) __bf16;
using f32x4  = __attribute__((ext_vector_type(4))) float;
using u32x4  = __attribute__((ext_vector_type(4))) unsigned;

#define Tn 256
#define Bn 64
#define Hn 1024

#define MFMA16(a, b, c) __builtin_amdgcn_mfma_f32_16x16x32_bf16((a), (b), (c), 0, 0, 0)

// ---------------------------------------------------------------------------
// Wg[l][k][unit] fp32 -> Wperm fragment-linear bf16:
// per (l,cb) a 128 KiB slab of 128 fragments x 64 lanes x 16 B.
// frag = ((p*4+kg)*8+kt)*2+nf  (p: 0=x,1=h; kg=K-window; kt; nf=col-half)
// lane = lhi*16 + l15; element (col=nf*16+l15, k=p*1024+kg*256+kt*32+lhi*8+j)
__global__ void convW(const float* __restrict__ Wi, const float* __restrict__ Wf,
                      const float* __restrict__ Wc, const float* __restrict__ Wo,
                      __bf16* __restrict__ Wperm) {
    int gid = blockIdx.x * 256 + threadIdx.x;      // 5*128*32*256 = 5,242,880
    int k8  = gid & 255;                           // 8-k chunk: k = k8*8
    int col = (gid >> 8) & 31;
    int cb  = (gid >> 13) & 127;
    int l   = gid >> 20;
    int g   = col >> 3;
    int uu  = col & 7;
    int unit = cb * 8 + uu;
    const float* Wg = (g == 0) ? Wi : (g == 1) ? Wf : (g == 2) ? Wc : Wo;
    const float* src = Wg + ((size_t)l * 2048 + k8 * 8) * 1024 + unit;
    bf16x8 v;
#pragma unroll
    for (int j = 0; j < 8; ++j) v[j] = (__bf16)src[(size_t)j * 1024];
    int p   = k8 >> 7;
    int kg  = (k8 >> 5) & 3;
    int kt  = (k8 >> 2) & 7;
    int lh  = k8 & 3;
    int nf  = col >> 4;
    int l15 = col & 15;
    int frag = ((p * 4 + kg) * 8 + kt) * 2 + nf;
    int lane = lh * 16 + l15;
    size_t dst = ((size_t)l * 128 + cb) * 131072 + (size_t)frag * 1024 + lane * 16;
    *(bf16x8*)((char*)Wperm + dst) = v;
}

// x[b][t][k] fp32 -> seq[t][b][k] bf16
__global__ void convX(const float* __restrict__ x, __bf16* __restrict__ seq) {
    int gid = blockIdx.x * 256 + threadIdx.x;      // 2,097,152
    int k8 = gid & 127;
    int b  = (gid >> 7) & 63;
    int t  = gid >> 13;
    const float* src = x + ((size_t)b * Tn + t) * Hn + k8 * 8;
    bf16x8 v;
#pragma unroll
    for (int j = 0; j < 8; ++j) v[j] = (__bf16)src[j];
    *(bf16x8*)(seq + (size_t)gid * 8) = v;
}

// ---------------------------------------------------------------------------
__device__ __forceinline__ void store_coh_u32(void* p, unsigned v) {
    asm volatile("global_store_dword %0, %1, off sc0 sc1" :: "v"(p), "v"(v) : "memory");
}
__device__ __forceinline__ void store_coh_u32x4(void* p, u32x4 v) {
    asm volatile("global_store_dwordx4 %0, %1, off sc0 sc1" :: "v"(p), "v"(v) : "memory");
}
__device__ __forceinline__ unsigned load_coh_u32(const void* p) {
    unsigned v;
    asm volatile("global_load_dword %0, %1, off sc0 sc1\n\ts_waitcnt vmcnt(0)"
                 : "=v"(v) : "v"(p) : "memory");
    return v;
}

// fast gates: v_exp_f32 computes 2^x; v_rcp_f32 ~1ulp
__device__ __forceinline__ float fsigmoid(float z) {
    return __builtin_amdgcn_rcpf(1.f + __builtin_amdgcn_exp2f(-1.44269504089f * z));
}
__device__ __forceinline__ float ftanh(float z) {
    return 1.f - 2.f * __builtin_amdgcn_rcpf(1.f + __builtin_amdgcn_exp2f(2.88539008178f * z));
}

// ---------------------------------------------------------------------------
// Persistent kernel. 256 blocks x 512 threads, 1 block/CU.
// bid: rb = bid&1 (batch half, 32 rows), cb = bid>>1 (8 units = 32 gate cols).
// waves: kg = (tid>>6)&3 (K-window), mg = tid>>8 (16 batch rows).
// Producer flags: wave w (of waves 0-3, rows 8w..8w+8) owns flag dword
// (rb*4+w)*128+cb. Consumer wave (kg,mg) needs rows [16mg,+16) x units
// [256kg,+256) = producer waves {2mg,2mg+1} x cb in [32kg,+32): 64 flags,
// polled 1 dword/lane (two 128B-aligned packed groups).
// LDS: [0,131072) weight slab (fragment-linear); [131072,149504) zp buffer.
__global__ __launch_bounds__(512, 2) void lstm_all(
    __bf16* __restrict__ seqA, __bf16* __restrict__ seqB,
    const __bf16* __restrict__ Wperm,
    const float* __restrict__ bip, const float* __restrict__ bfp,
    const float* __restrict__ bcp, const float* __restrict__ bop,
    unsigned* __restrict__ bar) {
    extern __shared__ char smem[];
    float* zp = (float*)(smem + 131072);           // [4][32][36]

    const int tid  = threadIdx.x;
    const int bid  = blockIdx.x;
    const int rb   = bid & 1;
    const int cb   = bid >> 1;
    const int lane = tid & 63;
    const int kg   = (tid >> 6) & 3;
    const int mg   = tid >> 8;
    const int l15  = lane & 15;
    const int lhi  = lane >> 4;
    const int arow = rb * 32 + mg * 16 + l15;      // batch row for A-frags
    const unsigned lane16 = (unsigned)lane << 4;

    unsigned* myflag = bar + (rb * 4 + (tid >> 6)) * 128 + cb;   // waves 0-3
    const unsigned* pollp = bar + (rb * 4 + 2 * mg + (lane >> 5)) * 128
                                + kg * 32 + (lane & 31);

    __bf16* inp  = seqA;
    __bf16* outp = seqB;

    for (int l = 0; l < 5; ++l) {
        // per-layer acquire: inv L1/L2 so cached reads of the ping-ponged
        // buffers can't hit stale lines from 2 layers ago.
        __builtin_amdgcn_fence(__ATOMIC_ACQUIRE, "agent");

        // ---- stage this layer's 128 KiB weight slab into LDS
        const char* Wl = (const char*)Wperm + ((size_t)l * 128 + cb) * 131072;
#pragma unroll
        for (int it = 0; it < 16; ++it) {
            int off = it * 8192 + tid * 16;
            *(bf16x8*)(smem + off) = *(const bf16x8*)(Wl + off);
        }
        // ---- per-layer epilogue constants + cell state (registers)
        float bia0 = 0.f, bia1 = 0.f, bia2 = 0.f, bia3 = 0.f, creg = 0.f;
        if (tid < 256) {
            int unit = cb * 8 + (tid & 7);
            bia0 = bip[l * 1024 + unit];
            bia1 = bfp[l * 1024 + unit];
            bia2 = bcp[l * 1024 + unit];
            bia3 = bop[l * 1024 + unit];
        }
        __syncthreads();                           // weights staged

        // ---- hold h-part B-fragments in registers (16 frags = 64 VGPR)
        bf16x8 bh[2][8];
#pragma unroll
        for (int nf = 0; nf < 2; ++nf)
#pragma unroll
            for (int kt = 0; kt < 8; ++kt)
                bh[nf][kt] = *(const bf16x8*)(smem +
                    ((unsigned)((((4 + kg) * 8 + kt) * 2 + nf) << 10)) + lane16);

        // ---- x-part GEMM for t = 0
        f32x4 acc0 = {}, acc1 = {};
        {
            const __bf16* ax = inp + (size_t)arow * Hn + kg * 256 + lhi * 8;
#pragma unroll
            for (int kt = 0; kt < 8; ++kt) {
                bf16x8 a  = *(const bf16x8*)(ax + kt * 32);
                bf16x8 b0 = *(const bf16x8*)(smem +
                    ((unsigned)(((kg * 8 + kt) * 2 + 0) << 10)) + lane16);
                bf16x8 b1 = *(const bf16x8*)(smem +
                    ((unsigned)(((kg * 8 + kt) * 2 + 1) << 10)) + lane16);
                acc0 = MFMA16(a, b0, acc0);
                acc1 = MFMA16(a, b1, acc1);
            }
        }

        for (int t = 0; t < Tn; ++t) {
            if (t > 0) {
                // ---- per-wave wait on 64 producer-wave flags
                unsigned target = (unsigned)(l * Tn + t);
                while (true) {
                    unsigned v = load_coh_u32(pollp);
                    if (__all((int)(v >= target))) break;
                }
                // ---- h-part GEMM for step t: NORMAL CACHED loads (L2 hit
                // for all but the first toucher per XCD), reg-resident B.
                const __bf16* ah = outp + ((size_t)(t - 1) * Bn + arow) * Hn
                                        + kg * 256 + lhi * 8;
                bf16x8 a0 = *(const bf16x8*)(ah);
                bf16x8 a1 = *(const bf16x8*)(ah + 32);
                bf16x8 a2 = *(const bf16x8*)(ah + 64);
                bf16x8 a3 = *(const bf16x8*)(ah + 96);
                bf16x8 a4 = *(const bf16x8*)(ah + 128);
                bf16x8 a5 = *(const bf16x8*)(ah + 160);
                bf16x8 a6 = *(const bf16x8*)(ah + 192);
                bf16x8 a7 = *(const bf16x8*)(ah + 224);
                acc0 = MFMA16(a0, bh[0][0], acc0); acc1 = MFMA16(a0, bh[1][0], acc1);
                acc0 = MFMA16(a1, bh[0][1], acc0); acc1 = MFMA16(a1, bh[1][1], acc1);
                acc0 = MFMA16(a2, bh[0][2], acc0); acc1 = MFMA16(a2, bh[1][2], acc1);
                acc0 = MFMA16(a3, bh[0][3], acc0); acc1 = MFMA16(a3, bh[1][3], acc1);
                acc0 = MFMA16(a4, bh[0][4], acc0); acc1 = MFMA16(a4, bh[1][4], acc1);
                acc0 = MFMA16(a5, bh[0][5], acc0); acc1 = MFMA16(a5, bh[1][5], acc1);
                acc0 = MFMA16(a6, bh[0][6], acc0); acc1 = MFMA16(a6, bh[1][6], acc1);
                acc0 = MFMA16(a7, bh[0][7], acc0); acc1 = MFMA16(a7, bh[1][7], acc1);
            }
            // ---- publish partials (D row = 4*lhi+j, col = 16*nf+l15)
#pragma unroll
            for (int j = 0; j < 4; ++j) {
                int row = kg * 32 + mg * 16 + 4 * lhi + j;
                zp[row * 36 + l15]      = acc0[j];
                zp[row * 36 + 16 + l15] = acc1[j];
            }
            __syncthreads();                       // sync1: zp ready
            // ---- reduce partials (waves 0-3), then release zp via sync2
            float z0 = 0.f, z1 = 0.f, z2 = 0.f, z3 = 0.f;
            if (tid < 256) {
                int uu = tid & 7, eb = tid >> 3;
                z0 = bia0; z1 = bia1; z2 = bia2; z3 = bia3;
#pragma unroll
                for (int k2 = 0; k2 < 4; ++k2) {
                    const float* zr = zp + (k2 * 32 + eb) * 36 + uu;
                    z0 += zr[0]; z1 += zr[8]; z2 += zr[16]; z3 += zr[24];
                }
            }
            __syncthreads();                       // sync2: zp reads done
            // ---- gates + state + packed h-store + per-wave flag (OFF-barrier)
            if (tid < 256) {
                __builtin_amdgcn_s_setprio(1);
                float ii = fsigmoid(z0);
                float ff = fsigmoid(z1);
                float gg = ftanh(z2);
                float oo = fsigmoid(z3);
                creg = creg * ff + ii * gg;
                float hv = oo * ftanh(creg);
                // pack 8 units of one batch row into one dwordx4 (shfl tree)
                unsigned hb = (unsigned)__builtin_bit_cast(unsigned short, (__bf16)hv);
                unsigned d  = hb | ((unsigned)__shfl_xor((int)hb, 1) << 16);
                unsigned d2 = (unsigned)__shfl_xor((int)d, 2);
                unsigned e0 = (unsigned)__shfl_xor((int)d, 4);
                unsigned e1 = (unsigned)__shfl_xor((int)d2, 4);
                if ((lane & 7) == 0) {
                    int eb = tid >> 3;
                    u32x4 v4 = {d, d2, e0, e1};
                    store_coh_u32x4(outp + (((size_t)t * Bn + rb * 32 + eb) * Hn
                                            + cb * 8), v4);
                }
                asm volatile("s_waitcnt vmcnt(0)" ::: "memory");  // own stores
                if ((tid & 63) == 0)
                    store_coh_u32(myflag, (unsigned)(l * Tn + t + 1));
                __builtin_amdgcn_s_setprio(0);
            }
            // ---- x-part GEMM for t+1 (h-independent -> hides flag latency)
            acc0 = (f32x4){}; acc1 = (f32x4){};
            if (t < Tn - 1) {
                const __bf16* ax = inp + ((size_t)(t + 1) * Bn + arow) * Hn
                                       + kg * 256 + lhi * 8;
#pragma unroll
                for (int kt = 0; kt < 8; ++kt) {
                    bf16x8 a  = *(const bf16x8*)(ax + kt * 32);
                    bf16x8 b0 = *(const bf16x8*)(smem +
                        ((unsigned)(((kg * 8 + kt) * 2 + 0) << 10)) + lane16);
                    bf16x8 b1 = *(const bf16x8*)(smem +
                        ((unsigned)(((kg * 8 + kt) * 2 + 1) << 10)) + lane16);
                    acc0 = MFMA16(a, b0, acc0);
                    acc1 = MFMA16(a, b1, acc1);
                }
            }
        }
        __bf16* tmp = outp; outp = inp; inp = tmp; // ping-pong
    }
}

// ---------------------------------------------------------------------------
// out[b] = dot(h5[T-1][b][:], Wfc) + bfc
__global__ void fc_kernel(const __bf16* __restrict__ seq, const float* __restrict__ Wfc,
                          const float* __restrict__ bfc, float* __restrict__ out) {
    int b = blockIdx.x;
    int tid = threadIdx.x;
    const __bf16* h = seq + ((size_t)(Tn - 1) * Bn + b) * Hn;
    float s = 0.f;
    for (int k = tid; k < Hn; k += 256) s += (float)h[k] * Wfc[k];
#pragma unroll
    for (int off = 32; off > 0; off >>= 1) s += __shfl_down(s, off);
    __shared__ float red[4];
    if ((tid & 63) == 0) red[tid >> 6] = s;
    __syncthreads();
    if (tid == 0) out[b] = red[0] + red[1] + red[2] + red[3] + bfc[0];
}

// ---------------------------------------------------------------------------
extern "C" void kernel_launch(void* const* d_in, const int* in_sizes, int n_in,
                              void* d_out, int out_size, void* d_ws, size_t ws_size,
                              hipStream_t stream) {
    const float* x   = (const float*)d_in[0];
    const float* Wi  = (const float*)d_in[1];
    const float* bi  = (const float*)d_in[2];
    const float* Wf  = (const float*)d_in[3];
    const float* bf  = (const float*)d_in[4];
    const float* Wc  = (const float*)d_in[5];
    const float* bc  = (const float*)d_in[6];
    const float* Wo  = (const float*)d_in[7];
    const float* bo  = (const float*)d_in[8];
    const float* Wfc = (const float*)d_in[9];
    const float* bfc = (const float*)d_in[10];

    char* ws = (char*)d_ws;
    __bf16*   Wperm = (__bf16*)ws;                                 // 83,886,080 B
    __bf16*   seqA  = (__bf16*)(ws + 83886080);                    // 33,554,432 B
    __bf16*   seqB  = (__bf16*)(ws + 83886080 + 33554432);         // 33,554,432 B
    unsigned* bar   = (unsigned*)(ws + 83886080 + 2 * 33554432);   //      4,096 B

    hipFuncSetAttribute((const void*)lstm_all,
                        hipFuncAttributeMaxDynamicSharedMemorySize, 149504);

    hipLaunchKernelGGL(convW, dim3(20480), dim3(256), 0, stream, Wi, Wf, Wc, Wo, Wperm);
    hipLaunchKernelGGL(convX, dim3(8192), dim3(256), 0, stream, x, seqA);
    hipMemsetAsync(bar, 0, 4096, stream);

    void* args[] = {(void*)&seqA, (void*)&seqB, (void*)&Wperm,
                    (void*)&bi, (void*)&bf, (void*)&bc, (void*)&bo, (void*)&bar};
    hipLaunchCooperativeKernel((const void*)lstm_all, dim3(256), dim3(512),
                               args, 149504, stream);

    // after 5 ping-pongs the final hidden sequence is in seqB
    hipLaunchKernelGGL(fc_kernel, dim3(64), dim3(256), 0, stream, seqB, Wfc, bfc,
                       (float*)d_out);
}